// Round 6
// baseline (257.287 us; speedup 1.0000x reference)
//
#include <hip/hip_runtime.h>
#include <hip/hip_bf16.h>
#include <stdint.h>

#define N1 8192
#define N2 16384
#define DIM 256
#define NSPLIT 16
#define BM 128
#define BN 128
#define BK 64
#define COLS_PER_SPLIT (N2 / NSPLIT)        // 1024
#define NT_PER_SPLIT (COLS_PER_SPLIT / BN)  // 8
#define NPART (NSPLIT * 2)                  // 32 partial top3 sets per row

typedef short v8s  __attribute__((ext_vector_type(8)));   // 8 x bf16 bits
typedef float f32x4 __attribute__((ext_vector_type(4)));

#define GLD16(g, l)                                                                         \
  __builtin_amdgcn_global_load_lds((const __attribute__((address_space(1))) uint32_t*)(g),  \
                                   (__attribute__((address_space(3))) uint32_t*)(l), 16, 0, 0)

__device__ __forceinline__ void top3_insert(float v, float& t0, float& t1, float& t2) {
    // invariant t0 >= t1 >= t2; 3 VALU ops
    float nt1 = __builtin_amdgcn_fmed3f(v, t0, t1);
    float nt2 = __builtin_amdgcn_fmed3f(v, t1, t2);
    t0 = fmaxf(t0, v);
    t1 = nt1;
    t2 = nt2;
}

// One wave per row over A then B: fp32 sumsq, rsqrt, emit bf16 normalized row.
__global__ __launch_bounds__(256) void normalize_kernel(
        const float* __restrict__ inA, const float* __restrict__ inB,
        __hip_bfloat16* __restrict__ outA, __hip_bfloat16* __restrict__ outB) {
    const int gw   = blockIdx.x * 4 + (threadIdx.x >> 6);
    const int lane = threadIdx.x & 63;
    const float* in;
    __hip_bfloat16* out;
    int row;
    if (gw < N1) { in = inA; out = outA; row = gw; }
    else         { in = inB; out = outB; row = gw - N1; }
    const float4 v = *(const float4*)(in + (size_t)row * DIM + lane * 4);
    float s = v.x * v.x + v.y * v.y + v.z * v.z + v.w * v.w;
    #pragma unroll
    for (int off = 32; off; off >>= 1) s += __shfl_xor(s, off, 64);
    const float inv = 1.0f / sqrtf(s);
    __hip_bfloat16 o[4];
    o[0] = __float2bfloat16(v.x * inv);
    o[1] = __float2bfloat16(v.y * inv);
    o[2] = __float2bfloat16(v.z * inv);
    o[3] = __float2bfloat16(v.w * inv);
    *(uint2*)(out + (size_t)row * DIM + lane * 4) = *(uint2*)o;
}

// Block: 4 waves over a 128x128 C-tile; wave = 64x64 (4rt x 4ct of 16x16).
// Per K-chunk (BK=64): A 128x64 (16 KB) + B 128x64 (16 KB) staged via
// global_load_lds width=16; XOR swizzle (slot16 = chunk ^ (row&7)) folded
// into the global-side lane permutation -> conflict-free ds_read_b128.
// NSPLIT=16 -> grid 1024 = 4 blocks/CU (VGPR 112, LDS 32 KB both allow it):
// barrier drains of one block overlap compute of the other three.
__global__ __launch_bounds__(256, 4) void gemm_top3_kernel(
        const __hip_bfloat16* __restrict__ A, const __hip_bfloat16* __restrict__ B,
        float* __restrict__ partial) {
    __shared__ char smem[16384 + 16384];
    char* tileA = smem;             // [128 rows][8 slots of 16B]
    char* tileB = smem + 16384;     // [128 cols][8 slots of 16B]

    const int tid  = threadIdx.x;
    const int wave = tid >> 6;
    const int lane = tid & 63;
    const int lo   = lane & 15;
    const int quad = lane >> 4;
    const int rb    = blockIdx.x >> 4;     // 64 row-blocks
    const int split = blockIdx.x & 15;     // consecutive blocks -> different XCDs
    const int row0 = rb * BM;
    const int C0   = split * COLS_PER_SPLIT;
    const int wr = (wave >> 1) * 64;       // wave row-half
    const int wc = (wave & 1) * 64;        // wave col-half

    // --- staging lane constants (8 lanes span one row's 8 slots of 16B) ---
    const int lr = lane >> 3;              // 0..7 : row-within-round
    const int s8 = lane & 7;               // 0..7 : physical LDS slot
    const int sx = s8 ^ lr;                // global 16B chunk this lane fetches

    const char* Agbase = (const char*)A + ((size_t)(row0 + wave * 32 + lr)) * 512 + sx * 16;
    const char* Bgbase = (const char*)B + ((size_t)(C0   + wave * 32 + lr)) * 512 + sx * 16;
    char* AldsBase = tileA + wave * 32 * 128;   // + j*1024 per 8-row round
    char* BldsBase = tileB + wave * 32 * 128;

    // --- ds_read offsets (swizzle: slot = (ks*4+quad) ^ (row&7)) ---
    int aoff[2], boff[2];
    #pragma unroll
    for (int ks = 0; ks < 2; ks++) {
        const int swz = ((ks * 4 + quad) ^ (lo & 7)) * 16;
        aoff[ks] = (wr + lo) * 128 + swz;
        boff[ks] = (wc + lo) * 128 + swz;
    }

    float t0[16], t1[16], t2[16];
    #pragma unroll
    for (int i = 0; i < 16; i++) { t0[i] = -1e30f; t1[i] = -1e30f; t2[i] = -1e30f; }

    for (int nt = 0; nt < NT_PER_SPLIT; ++nt) {
        f32x4 acc[4][4];
        #pragma unroll
        for (int kk = 0; kk < 4; kk++) {
            __syncthreads();   // previous chunk's ds_reads done; buffers free
            #pragma unroll
            for (int j = 0; j < 4; j++)
                GLD16(Agbase + (size_t)j * 4096 + kk * 128, AldsBase + j * 1024);
            #pragma unroll
            for (int j = 0; j < 4; j++)
                GLD16(Bgbase + (size_t)nt * 65536 + (size_t)j * 4096 + kk * 128,
                      BldsBase + j * 1024);
            __syncthreads();   // staging drained (vmcnt(0) before barrier)
            #pragma unroll
            for (int ks = 0; ks < 2; ks++) {
                v8s af[4];
                #pragma unroll
                for (int rt = 0; rt < 4; rt++)
                    af[rt] = *(const v8s*)(tileA + aoff[ks] + rt * 2048);
                #pragma unroll
                for (int ct = 0; ct < 4; ct++) {
                    v8s bf = *(const v8s*)(tileB + boff[ks] + ct * 2048);
                    #pragma unroll
                    for (int rt = 0; rt < 4; rt++) {
                        if (kk == 0 && ks == 0)
                            acc[rt][ct] = __builtin_amdgcn_mfma_f32_16x16x32_bf16(
                                af[rt], bf, (f32x4){0.f, 0.f, 0.f, 0.f}, 0, 0, 0);
                        else
                            acc[rt][ct] = __builtin_amdgcn_mfma_f32_16x16x32_bf16(
                                af[rt], bf, acc[rt][ct], 0, 0, 0);
                    }
                }
            }
        }
        // fold this N-tile's 64 C-values/lane into the running top3
        #pragma unroll
        for (int rt = 0; rt < 4; rt++)
            #pragma unroll
            for (int r = 0; r < 4; r++) {
                const int i = rt * 4 + r;
                #pragma unroll
                for (int ct = 0; ct < 4; ct++)
                    top3_insert(acc[rt][ct][r], t0[i], t1[i], t2[i]);
            }
    }

    // merge across the 16 lanes sharing rows (different col residues)
    #pragma unroll
    for (int step = 1; step < 16; step <<= 1) {
        #pragma unroll
        for (int i = 0; i < 16; i++) {
            float b0 = __shfl_xor(t0[i], step, 64);
            float b1 = __shfl_xor(t1[i], step, 64);
            float b2 = __shfl_xor(t2[i], step, 64);
            top3_insert(b0, t0[i], t1[i], t2[i]);
            top3_insert(b1, t0[i], t1[i], t2[i]);
            top3_insert(b2, t0[i], t1[i], t2[i]);
        }
    }

    if (lo == 0) {
        #pragma unroll
        for (int rt = 0; rt < 4; rt++)
            #pragma unroll
            for (int r = 0; r < 4; r++) {
                const int i = rt * 4 + r;
                const int row = row0 + wr + rt * 16 + quad * 4 + r;
                float* p = partial + ((size_t)row * NPART + (split * 2 + (wave & 1))) * 3;
                p[0] = t0[i]; p[1] = t1[i]; p[2] = t2[i];
            }
    }
}

__global__ __launch_bounds__(256) void merge_kernel(
        const float* __restrict__ partial, float* __restrict__ out) {
    const int row = blockIdx.x * 256 + threadIdx.x;
    if (row >= N1) return;
    const float* p = partial + (size_t)row * NPART * 3;
    float t0 = -1e30f, t1 = -1e30f, t2 = -1e30f;
    #pragma unroll
    for (int i = 0; i < NPART * 3; i++) top3_insert(p[i], t0, t1, t2);
    out[row] = (t0 + t1 + t2) * (1.0f / 3.0f);
}

extern "C" void kernel_launch(void* const* d_in, const int* in_sizes, int n_in,
                              void* d_out, int out_size, void* d_ws, size_t ws_size,
                              hipStream_t stream) {
    const float* tA = (const float*)d_in[0];
    const float* tB = (const float*)d_in[1];
    float* out = (float*)d_out;

    __hip_bfloat16* An = (__hip_bfloat16*)d_ws;
    __hip_bfloat16* Bn = An + (size_t)N1 * DIM;
    float* partial = (float*)(Bn + (size_t)N2 * DIM);

    normalize_kernel<<<(N1 + N2) / 4, 256, 0, stream>>>(tA, tB, An, Bn);
    gemm_top3_kernel<<<(N1 / BM) * NSPLIT, 256, 0, stream>>>(An, Bn, partial);
    merge_kernel<<<N1 / 256, 256, 0, stream>>>(partial, out);
}

// Round 7
// 158.832 us; speedup vs baseline: 1.6199x; 1.6199x over previous
//
#include <hip/hip_runtime.h>
#include <hip/hip_bf16.h>
#include <stdint.h>

#define N1 8192
#define N2 16384
#define DIM 256
#define NSPLIT 16
#define BM 128
#define BN 128
#define BK 64
#define COLS_PER_SPLIT (N2 / NSPLIT)        // 1024
#define NT_PER_SPLIT (COLS_PER_SPLIT / BN)  // 8
#define NPART (NSPLIT * 2)                  // 32 partial top3 sets per row

typedef short v8s  __attribute__((ext_vector_type(8)));   // 8 x bf16 bits
typedef float f32x4 __attribute__((ext_vector_type(4)));

#define GLD16(g, l)                                                                         \
  __builtin_amdgcn_global_load_lds((const __attribute__((address_space(1))) uint32_t*)(g),  \
                                   (__attribute__((address_space(3))) uint32_t*)(l), 16, 0, 0)

__device__ __forceinline__ void top3_insert(float v, float& t0, float& t1, float& t2) {
    // invariant t0 >= t1 >= t2; 3 VALU ops
    float nt1 = __builtin_amdgcn_fmed3f(v, t0, t1);
    float nt2 = __builtin_amdgcn_fmed3f(v, t1, t2);
    t0 = fmaxf(t0, v);
    t1 = nt1;
    t2 = nt2;
}

// One wave per row over A then B: fp32 sumsq, rsqrt, emit bf16 normalized row.
__global__ __launch_bounds__(256) void normalize_kernel(
        const float* __restrict__ inA, const float* __restrict__ inB,
        __hip_bfloat16* __restrict__ outA, __hip_bfloat16* __restrict__ outB) {
    const int gw   = blockIdx.x * 4 + (threadIdx.x >> 6);
    const int lane = threadIdx.x & 63;
    const float* in;
    __hip_bfloat16* out;
    int row;
    if (gw < N1) { in = inA; out = outA; row = gw; }
    else         { in = inB; out = outB; row = gw - N1; }
    const float4 v = *(const float4*)(in + (size_t)row * DIM + lane * 4);
    float s = v.x * v.x + v.y * v.y + v.z * v.z + v.w * v.w;
    #pragma unroll
    for (int off = 32; off; off >>= 1) s += __shfl_xor(s, off, 64);
    const float inv = 1.0f / sqrtf(s);
    __hip_bfloat16 o[4];
    o[0] = __float2bfloat16(v.x * inv);
    o[1] = __float2bfloat16(v.y * inv);
    o[2] = __float2bfloat16(v.z * inv);
    o[3] = __float2bfloat16(v.w * inv);
    *(uint2*)(out + (size_t)row * DIM + lane * 4) = *(uint2*)o;
}

// Block: 4 waves over a 128x128 C-tile; wave = 64x64 (4rt x 4ct of 16x16).
// Per K-chunk (BK=64): A 128x64 (16 KB) + B 128x64 (16 KB) staged via
// global_load_lds width=16; XOR swizzle (slot16 = chunk ^ (row&7)) folded
// into the global-side lane permutation -> conflict-free ds_read_b128.
// NSPLIT=16 -> grid 1024 = 4 blocks/CU. launch_bounds min-waves stays 2:
// R5 showed (256,4) makes the allocator squeeze to 64 VGPR and spill
// (WRITE_SIZE 341 MB); at 112 VGPR the HW reaches 4 blocks/CU on its own.
__global__ __launch_bounds__(256, 2) void gemm_top3_kernel(
        const __hip_bfloat16* __restrict__ A, const __hip_bfloat16* __restrict__ B,
        float* __restrict__ partial) {
    __shared__ char smem[16384 + 16384];
    char* tileA = smem;             // [128 rows][8 slots of 16B]
    char* tileB = smem + 16384;     // [128 cols][8 slots of 16B]

    const int tid  = threadIdx.x;
    const int wave = tid >> 6;
    const int lane = tid & 63;
    const int lo   = lane & 15;
    const int quad = lane >> 4;
    const int rb    = blockIdx.x >> 4;     // 64 row-blocks
    const int split = blockIdx.x & 15;     // consecutive blocks -> different XCDs
    const int row0 = rb * BM;
    const int C0   = split * COLS_PER_SPLIT;
    const int wr = (wave >> 1) * 64;       // wave row-half
    const int wc = (wave & 1) * 64;        // wave col-half

    // --- staging lane constants (8 lanes span one row's 8 slots of 16B) ---
    const int lr = lane >> 3;              // 0..7 : row-within-round
    const int s8 = lane & 7;               // 0..7 : physical LDS slot
    const int sx = s8 ^ lr;                // global 16B chunk this lane fetches

    const char* Agbase = (const char*)A + ((size_t)(row0 + wave * 32 + lr)) * 512 + sx * 16;
    const char* Bgbase = (const char*)B + ((size_t)(C0   + wave * 32 + lr)) * 512 + sx * 16;
    char* AldsBase = tileA + wave * 32 * 128;   // + j*1024 per 8-row round
    char* BldsBase = tileB + wave * 32 * 128;

    // --- ds_read offsets (swizzle: slot = (ks*4+quad) ^ (row&7)) ---
    int aoff[2], boff[2];
    #pragma unroll
    for (int ks = 0; ks < 2; ks++) {
        const int swz = ((ks * 4 + quad) ^ (lo & 7)) * 16;
        aoff[ks] = (wr + lo) * 128 + swz;
        boff[ks] = (wc + lo) * 128 + swz;
    }

    float t0[16], t1[16], t2[16];
    #pragma unroll
    for (int i = 0; i < 16; i++) { t0[i] = -1e30f; t1[i] = -1e30f; t2[i] = -1e30f; }

    for (int nt = 0; nt < NT_PER_SPLIT; ++nt) {
        f32x4 acc[4][4];
        #pragma unroll
        for (int kk = 0; kk < 4; kk++) {
            __syncthreads();   // previous chunk's ds_reads done; buffers free
            #pragma unroll
            for (int j = 0; j < 4; j++)
                GLD16(Agbase + (size_t)j * 4096 + kk * 128, AldsBase + j * 1024);
            #pragma unroll
            for (int j = 0; j < 4; j++)
                GLD16(Bgbase + (size_t)nt * 65536 + (size_t)j * 4096 + kk * 128,
                      BldsBase + j * 1024);
            __syncthreads();   // staging drained (vmcnt(0) before barrier)
            #pragma unroll
            for (int ks = 0; ks < 2; ks++) {
                v8s af[4];
                #pragma unroll
                for (int rt = 0; rt < 4; rt++)
                    af[rt] = *(const v8s*)(tileA + aoff[ks] + rt * 2048);
                #pragma unroll
                for (int ct = 0; ct < 4; ct++) {
                    v8s bf = *(const v8s*)(tileB + boff[ks] + ct * 2048);
                    #pragma unroll
                    for (int rt = 0; rt < 4; rt++) {
                        if (kk == 0 && ks == 0)
                            acc[rt][ct] = __builtin_amdgcn_mfma_f32_16x16x32_bf16(
                                af[rt], bf, (f32x4){0.f, 0.f, 0.f, 0.f}, 0, 0, 0);
                        else
                            acc[rt][ct] = __builtin_amdgcn_mfma_f32_16x16x32_bf16(
                                af[rt], bf, acc[rt][ct], 0, 0, 0);
                    }
                }
            }
        }
        // fold this N-tile's 64 C-values/lane into the running top3
        #pragma unroll
        for (int rt = 0; rt < 4; rt++)
            #pragma unroll
            for (int r = 0; r < 4; r++) {
                const int i = rt * 4 + r;
                #pragma unroll
                for (int ct = 0; ct < 4; ct++)
                    top3_insert(acc[rt][ct][r], t0[i], t1[i], t2[i]);
            }
    }

    // merge across the 16 lanes sharing rows (different col residues)
    #pragma unroll
    for (int step = 1; step < 16; step <<= 1) {
        #pragma unroll
        for (int i = 0; i < 16; i++) {
            float b0 = __shfl_xor(t0[i], step, 64);
            float b1 = __shfl_xor(t1[i], step, 64);
            float b2 = __shfl_xor(t2[i], step, 64);
            top3_insert(b0, t0[i], t1[i], t2[i]);
            top3_insert(b1, t0[i], t1[i], t2[i]);
            top3_insert(b2, t0[i], t1[i], t2[i]);
        }
    }

    if (lo == 0) {
        #pragma unroll
        for (int rt = 0; rt < 4; rt++)
            #pragma unroll
            for (int r = 0; r < 4; r++) {
                const int i = rt * 4 + r;
                const int row = row0 + wr + rt * 16 + quad * 4 + r;
                float* p = partial + ((size_t)row * NPART + (split * 2 + (wave & 1))) * 3;
                p[0] = t0[i]; p[1] = t1[i]; p[2] = t2[i];
            }
    }
}

__global__ __launch_bounds__(256) void merge_kernel(
        const float* __restrict__ partial, float* __restrict__ out) {
    const int row = blockIdx.x * 256 + threadIdx.x;
    if (row >= N1) return;
    const float* p = partial + (size_t)row * NPART * 3;
    float t0 = -1e30f, t1 = -1e30f, t2 = -1e30f;
    #pragma unroll
    for (int i = 0; i < NPART * 3; i++) top3_insert(p[i], t0, t1, t2);
    out[row] = (t0 + t1 + t2) * (1.0f / 3.0f);
}

extern "C" void kernel_launch(void* const* d_in, const int* in_sizes, int n_in,
                              void* d_out, int out_size, void* d_ws, size_t ws_size,
                              hipStream_t stream) {
    const float* tA = (const float*)d_in[0];
    const float* tB = (const float*)d_in[1];
    float* out = (float*)d_out;

    __hip_bfloat16* An = (__hip_bfloat16*)d_ws;
    __hip_bfloat16* Bn = An + (size_t)N1 * DIM;
    float* partial = (float*)(Bn + (size_t)N2 * DIM);

    normalize_kernel<<<(N1 + N2) / 4, 256, 0, stream>>>(tA, tB, An, Bn);
    gemm_top3_kernel<<<(N1 / BM) * NSPLIT, 256, 0, stream>>>(An, Bn, partial);
    merge_kernel<<<N1 / 256, 256, 0, stream>>>(partial, out);
}

// Round 8
// 152.510 us; speedup vs baseline: 1.6870x; 1.0415x over previous
//
#include <hip/hip_runtime.h>
#include <hip/hip_bf16.h>
#include <stdint.h>

#define N1 8192
#define N2 16384
#define DIM 256
#define NSPLIT 16
#define BM 128
#define BN 128
#define BK 128
#define COLS_PER_SPLIT (N2 / NSPLIT)        // 1024
#define NT_PER_SPLIT (COLS_PER_SPLIT / BN)  // 8
#define NPART (NSPLIT * 2)                  // 32 partial top3 sets per row

typedef short v8s  __attribute__((ext_vector_type(8)));   // 8 x bf16 bits
typedef float f32x4 __attribute__((ext_vector_type(4)));

#define GLD16(g, l)                                                                         \
  __builtin_amdgcn_global_load_lds((const __attribute__((address_space(1))) uint32_t*)(g),  \
                                   (__attribute__((address_space(3))) uint32_t*)(l), 16, 0, 0)

__device__ __forceinline__ void top3_insert(float v, float& t0, float& t1, float& t2) {
    // invariant t0 >= t1 >= t2; 3 VALU ops
    float nt1 = __builtin_amdgcn_fmed3f(v, t0, t1);
    float nt2 = __builtin_amdgcn_fmed3f(v, t1, t2);
    t0 = fmaxf(t0, v);
    t1 = nt1;
    t2 = nt2;
}

// One wave per row over A then B: fp32 sumsq, rsqrt, emit bf16 normalized row.
__global__ __launch_bounds__(256) void normalize_kernel(
        const float* __restrict__ inA, const float* __restrict__ inB,
        __hip_bfloat16* __restrict__ outA, __hip_bfloat16* __restrict__ outB) {
    const int gw   = blockIdx.x * 4 + (threadIdx.x >> 6);
    const int lane = threadIdx.x & 63;
    const float* in;
    __hip_bfloat16* out;
    int row;
    if (gw < N1) { in = inA; out = outA; row = gw; }
    else         { in = inB; out = outB; row = gw - N1; }
    const float4 v = *(const float4*)(in + (size_t)row * DIM + lane * 4);
    float s = v.x * v.x + v.y * v.y + v.z * v.z + v.w * v.w;
    #pragma unroll
    for (int off = 32; off; off >>= 1) s += __shfl_xor(s, off, 64);
    const float inv = 1.0f / sqrtf(s);
    __hip_bfloat16 o[4];
    o[0] = __float2bfloat16(v.x * inv);
    o[1] = __float2bfloat16(v.y * inv);
    o[2] = __float2bfloat16(v.z * inv);
    o[3] = __float2bfloat16(v.w * inv);
    *(uint2*)(out + (size_t)row * DIM + lane * 4) = *(uint2*)o;
}

// Block: 4 waves over a 128x128 C-tile; wave = 64x64 (4rt x 4ct of 16x16).
// BK=128: per K-chunk A 128x128 (32 KB) + B 128x128 (32 KB) staged via
// global_load_lds width=16. 16 barrier-rounds/block (vs 32 at BK=64): we are
// register-capped at 2 blocks/CU (VGPR 112 + 64 AGPR acc ~ 176/wave), so the
// 64 KB LDS costs no occupancy and halves the exposed vmcnt(0) drains.
// XOR swizzle slot16 = chunk ^ (row&15) folded into the global-side lane
// permutation -> <=2-way (free) ds_read_b128 conflicts, zero ds_writes.
__global__ __launch_bounds__(256, 2) void gemm_top3_kernel(
        const __hip_bfloat16* __restrict__ A, const __hip_bfloat16* __restrict__ B,
        float* __restrict__ partial) {
    __shared__ char smem[32768 + 32768];
    char* tileA = smem;             // [128 rows][16 slots of 16B]  row stride 256 B
    char* tileB = smem + 32768;     // [128 cols][16 slots of 16B]

    const int tid  = threadIdx.x;
    const int wave = tid >> 6;
    const int lane = tid & 63;
    const int lo   = lane & 15;
    const int quad = lane >> 4;
    const int rb    = blockIdx.x >> 4;     // 64 row-blocks
    const int split = blockIdx.x & 15;     // consecutive blocks -> different XCDs
    const int row0 = rb * BM;
    const int C0   = split * COLS_PER_SPLIT;
    const int wr = (wave >> 1) * 64;       // wave row-half
    const int wc = (wave & 1) * 64;        // wave col-half

    // --- staging lane constants (16 lanes span one row's 16 slots of 16B) ---
    const int lr  = lane >> 4;             // 0..3 : row-within-round
    const int s16 = lane & 15;             // 0..15: physical LDS slot

    const char* Agbase = (const char*)A + ((size_t)(row0 + wave * 32 + lr)) * 512;
    const char* Bgbase = (const char*)B + ((size_t)(C0   + wave * 32 + lr)) * 512;
    char* AldsBase = tileA + wave * 32 * 256;   // + j*1024 per 4-row round
    char* BldsBase = tileB + wave * 32 * 256;

    // --- ds_read offsets (swizzle: slot = (ks*4+quad) ^ (row&15)) ---
    int aoff[4], boff[4];
    #pragma unroll
    for (int ks = 0; ks < 4; ks++) {
        const int swz = ((ks * 4 + quad) ^ lo) * 16;
        aoff[ks] = (wr + lo) * 256 + swz;
        boff[ks] = (wc + lo) * 256 + swz;
    }

    float t0[16], t1[16], t2[16];
    #pragma unroll
    for (int i = 0; i < 16; i++) { t0[i] = -1e30f; t1[i] = -1e30f; t2[i] = -1e30f; }

    for (int nt = 0; nt < NT_PER_SPLIT; ++nt) {
        f32x4 acc[4][4];
        #pragma unroll
        for (int kk = 0; kk < 2; kk++) {
            __syncthreads();   // previous round's ds_reads done; buffers free
            #pragma unroll
            for (int j = 0; j < 8; j++) {
                const int sxj = (s16 ^ ((j * 4 + lr) & 15)) * 16;
                GLD16(Agbase + (size_t)j * 2048 + kk * 256 + sxj, AldsBase + j * 1024);
                GLD16(Bgbase + (size_t)nt * 65536 + (size_t)j * 2048 + kk * 256 + sxj,
                      BldsBase + j * 1024);
            }
            __syncthreads();   // staging drained (vmcnt(0) before barrier)
            #pragma unroll
            for (int ks = 0; ks < 4; ks++) {
                v8s af[4];
                #pragma unroll
                for (int rt = 0; rt < 4; rt++)
                    af[rt] = *(const v8s*)(tileA + aoff[ks] + rt * 4096);
                #pragma unroll
                for (int ct = 0; ct < 4; ct++) {
                    v8s bf = *(const v8s*)(tileB + boff[ks] + ct * 4096);
                    #pragma unroll
                    for (int rt = 0; rt < 4; rt++) {
                        if (kk == 0 && ks == 0)
                            acc[rt][ct] = __builtin_amdgcn_mfma_f32_16x16x32_bf16(
                                af[rt], bf, (f32x4){0.f, 0.f, 0.f, 0.f}, 0, 0, 0);
                        else
                            acc[rt][ct] = __builtin_amdgcn_mfma_f32_16x16x32_bf16(
                                af[rt], bf, acc[rt][ct], 0, 0, 0);
                    }
                }
            }
        }
        // fold this N-tile's 64 C-values/lane into the running top3
        #pragma unroll
        for (int rt = 0; rt < 4; rt++)
            #pragma unroll
            for (int r = 0; r < 4; r++) {
                const int i = rt * 4 + r;
                #pragma unroll
                for (int ct = 0; ct < 4; ct++)
                    top3_insert(acc[rt][ct][r], t0[i], t1[i], t2[i]);
            }
    }

    // merge across the 16 lanes sharing rows (different col residues)
    #pragma unroll
    for (int step = 1; step < 16; step <<= 1) {
        #pragma unroll
        for (int i = 0; i < 16; i++) {
            float b0 = __shfl_xor(t0[i], step, 64);
            float b1 = __shfl_xor(t1[i], step, 64);
            float b2 = __shfl_xor(t2[i], step, 64);
            top3_insert(b0, t0[i], t1[i], t2[i]);
            top3_insert(b1, t0[i], t1[i], t2[i]);
            top3_insert(b2, t0[i], t1[i], t2[i]);
        }
    }

    if (lo == 0) {
        #pragma unroll
        for (int rt = 0; rt < 4; rt++)
            #pragma unroll
            for (int r = 0; r < 4; r++) {
                const int i = rt * 4 + r;
                const int row = row0 + wr + rt * 16 + quad * 4 + r;
                float* p = partial + ((size_t)row * NPART + (split * 2 + (wave & 1))) * 3;
                p[0] = t0[i]; p[1] = t1[i]; p[2] = t2[i];
            }
    }
}

__global__ __launch_bounds__(256) void merge_kernel(
        const float* __restrict__ partial, float* __restrict__ out) {
    const int row = blockIdx.x * 256 + threadIdx.x;
    if (row >= N1) return;
    const float* p = partial + (size_t)row * NPART * 3;
    float t0 = -1e30f, t1 = -1e30f, t2 = -1e30f;
    #pragma unroll
    for (int i = 0; i < NPART * 3; i++) top3_insert(p[i], t0, t1, t2);
    out[row] = (t0 + t1 + t2) * (1.0f / 3.0f);
}

extern "C" void kernel_launch(void* const* d_in, const int* in_sizes, int n_in,
                              void* d_out, int out_size, void* d_ws, size_t ws_size,
                              hipStream_t stream) {
    const float* tA = (const float*)d_in[0];
    const float* tB = (const float*)d_in[1];
    float* out = (float*)d_out;

    __hip_bfloat16* An = (__hip_bfloat16*)d_ws;
    __hip_bfloat16* Bn = An + (size_t)N1 * DIM;
    float* partial = (float*)(Bn + (size_t)N2 * DIM);

    normalize_kernel<<<(N1 + N2) / 4, 256, 0, stream>>>(tA, tB, An, Bn);
    gemm_top3_kernel<<<(N1 / BM) * NSPLIT, 256, 0, stream>>>(An, Bn, partial);
    merge_kernel<<<N1 / 256, 256, 0, stream>>>(partial, out);
}